// Round 1
// baseline (2005.737 us; speedup 1.0000x reference)
//
#include <hip/hip_runtime.h>
#include <hip/hip_bf16.h>
#include <math.h>

typedef __bf16 bf16_t;
typedef __attribute__((ext_vector_type(8))) __bf16 bf16x8;
typedef __attribute__((ext_vector_type(4))) __bf16 bf16x4;
typedef __attribute__((ext_vector_type(4))) float f32x4;

#define DEVI __device__ __forceinline__

constexpr int B_SZ = 16384, DIN = 2048, DK = 2048, DV = 2048, NH = 16, DOUT = 512;

DEVI void load_lds16(const void* gptr, void* lptr) {
  __builtin_amdgcn_global_load_lds(
      (const __attribute__((address_space(1))) unsigned int*)gptr,
      (__attribute__((address_space(3))) unsigned int*)lptr,
      16, 0, 0);
}

// ---------------------------------------------------------------------------
// Generic bf16 GEMM, B given transposed (Bt[n][k]), C = A @ B (+ epilogue)
// Tile 128x128, BK=32, 256 threads (4 waves, each 64x64 via 4x4 of 16x16x32).
// EPI: 0 plain bf16, 1 relu+1e-4 bf16, 2 +bias bf16, 3 *z bf16 (head=blockIdx.z),
//      4 sigmoid-gate mix bf16, 5 +bias f32
// ---------------------------------------------------------------------------
template <int EPI>
__global__ __launch_bounds__(256) void gemm_bt(
    const bf16_t* __restrict__ A, int lda, long aZ,
    const bf16_t* __restrict__ Bt, int ldb, long bZ,
    void* __restrict__ Cv, int ldc, long cZ, int K,
    const float* __restrict__ aux1,   // bias
    const float* __restrict__ aux2) { // z (EPI3) or x (EPI4)
  __shared__ __align__(16) bf16_t As[128 * 32];
  __shared__ __align__(16) bf16_t Bs[128 * 32];
  const int tid = threadIdx.x;
  const int bn = blockIdx.x, bm = blockIdx.y, bz = blockIdx.z;
  const int lane = tid & 63, w = tid >> 6;
  const int wm = (w & 1) * 64, wn = (w >> 1) * 64;
  const int ln = lane & 15, qd = lane >> 4;

  const bf16_t* Ab = A + (long)bm * 128 * lda + (long)bz * aZ;
  const bf16_t* Bb = Bt + (long)bn * 128 * ldb + (long)bz * bZ;

  const int srow = tid >> 2, scol = (tid & 3) * 8;  // 64 rows x 32 k per issue

  f32x4 acc[4][4] = {};

  for (int k0 = 0; k0 < K; k0 += 32) {
#pragma unroll
    for (int it = 0; it < 2; ++it) {
      load_lds16(Ab + (long)(srow + it * 64) * lda + k0 + scol, &As[it * 2048 + tid * 8]);
      load_lds16(Bb + (long)(srow + it * 64) * ldb + k0 + scol, &Bs[it * 2048 + tid * 8]);
    }
    __syncthreads();
    bf16x8 af[4], bfr[4];
#pragma unroll
    for (int i = 0; i < 4; ++i)
      af[i] = *(const bf16x8*)&As[(wm + i * 16 + ln) * 32 + qd * 8];
#pragma unroll
    for (int j = 0; j < 4; ++j)
      bfr[j] = *(const bf16x8*)&Bs[(wn + j * 16 + ln) * 32 + qd * 8];
#pragma unroll
    for (int i = 0; i < 4; ++i)
#pragma unroll
      for (int j = 0; j < 4; ++j)
        acc[i][j] = __builtin_amdgcn_mfma_f32_16x16x32_bf16(af[i], bfr[j], acc[i][j], 0, 0, 0);
    __syncthreads();
  }

#pragma unroll
  for (int i = 0; i < 4; ++i) {
#pragma unroll
    for (int j = 0; j < 4; ++j) {
#pragma unroll
      for (int r = 0; r < 4; ++r) {
        const int row = bm * 128 + wm + i * 16 + qd * 4 + r;
        const int col = bn * 128 + wn + j * 16 + ln;
        const long cidx = (long)row * ldc + (long)bz * cZ + col;
        float val = acc[i][j][r];
        if (EPI == 0) {
          ((bf16_t*)Cv)[cidx] = (bf16_t)val;
        } else if (EPI == 1) {
          val = fmaxf(val, 0.f) + 1e-4f;
          ((bf16_t*)Cv)[cidx] = (bf16_t)val;
        } else if (EPI == 2) {
          val += aux1[col];
          ((bf16_t*)Cv)[cidx] = (bf16_t)val;
        } else if (EPI == 3) {
          val *= aux2[(long)row * NH + bz];
          ((bf16_t*)Cv)[cidx] = (bf16_t)val;
        } else if (EPI == 4) {
          const float g = 1.f / (1.f + __expf(-(val + aux1[col])));
          const float op = (float)A[(long)row * lda + col];  // concat cols [0,2048)
          const float xx = aux2[(long)row * DIN + col];
          ((bf16_t*)Cv)[cidx] = (bf16_t)(g * op + (1.f - g) * xx);
        } else if (EPI == 5) {
          ((float*)Cv)[cidx] = val + aux1[col];
        }
      }
    }
  }
}

// x f32 -> bf16 into concat buffer cols [2048, 4096)
__global__ __launch_bounds__(256) void cvt_x_kernel(const float* __restrict__ x,
                                                    bf16_t* __restrict__ cc) {
  const long i = ((long)blockIdx.x * 256 + threadIdx.x) * 4;
  const long row = i >> 11;
  const int col = (int)(i & 2047);
  const float4 f = *(const float4*)&x[i];
  bf16x4 o;
  o[0] = (bf16_t)f.x; o[1] = (bf16_t)f.y; o[2] = (bf16_t)f.z; o[3] = (bf16_t)f.w;
  *(bf16x4*)&cc[row * 4096 + 2048 + col] = o;
}

// W [R][C] f32 -> Wt [C][R] bf16
__global__ __launch_bounds__(256) void transpose_f32_bf16(const float* __restrict__ in,
                                                          bf16_t* __restrict__ out,
                                                          int R, int C) {
  __shared__ bf16_t tile[32][33];
  const int c0 = blockIdx.x * 32, r0 = blockIdx.y * 32;
  for (int i = threadIdx.y; i < 32; i += 8)
    tile[i][threadIdx.x] = (bf16_t)in[(long)(r0 + i) * C + c0 + threadIdx.x];
  __syncthreads();
  for (int i = threadIdx.y; i < 32; i += 8)
    out[(long)(c0 + i) * R + r0 + threadIdx.x] = tile[threadIdx.x][i];
}

// ksum[c] = sum_b k[b][c]
__global__ __launch_bounds__(256) void ksum_kernel(const bf16_t* __restrict__ k,
                                                   float* __restrict__ ksum) {
  const int col = blockIdx.x * 256 + threadIdx.x;
  const int r0 = blockIdx.y * 256;
  float s = 0.f;
  for (int r = 0; r < 256; ++r) s += (float)k[(long)(r0 + r) * DK + col];
  atomicAdd(&ksum[col], s);
}

// P[h][e][d] += sum_b v[b, h*128+e] * k[b, h*128+d]   (this is kv^T = Bt for att GEMM)
__global__ __launch_bounds__(256) void kv_kernel(const bf16_t* __restrict__ kp,
                                                 const bf16_t* __restrict__ vp,
                                                 float* __restrict__ P) {
  const int h = blockIdx.x, sp = blockIdx.y;
  const int t = threadIdx.x;
  __shared__ __align__(16) bf16_t kS[64 * 128];
  __shared__ __align__(16) bf16_t vS[64 * 128];
  const int e0 = (t >> 4) * 8, d0 = (t & 15) * 8;
  const int srow = t >> 4, scol = (t & 15) * 8;
  float acc[8][8] = {};
  const long base = (long)sp * 512 * DK + h * 128;
  for (int c0 = 0; c0 < 512; c0 += 64) {
#pragma unroll
    for (int it = 0; it < 4; ++it) {
      load_lds16(kp + base + (long)(c0 + it * 16 + srow) * DK + scol, &kS[it * 2048 + t * 8]);
      load_lds16(vp + base + (long)(c0 + it * 16 + srow) * DV + scol, &vS[it * 2048 + t * 8]);
    }
    __syncthreads();
    for (int bb = 0; bb < 64; ++bb) {
      const bf16x8 vv = *(const bf16x8*)&vS[bb * 128 + e0];
      const bf16x8 kk = *(const bf16x8*)&kS[bb * 128 + d0];
      float vf[8], kf[8];
#pragma unroll
      for (int r = 0; r < 8; ++r) { vf[r] = (float)vv[r]; kf[r] = (float)kk[r]; }
#pragma unroll
      for (int a = 0; a < 8; ++a)
#pragma unroll
        for (int b2 = 0; b2 < 8; ++b2) acc[a][b2] += vf[a] * kf[b2];
    }
    __syncthreads();
  }
  float* Ph = P + (long)h * 16384;
#pragma unroll
  for (int a = 0; a < 8; ++a)
#pragma unroll
    for (int b2 = 0; b2 < 8; ++b2)
      atomicAdd(&Ph[(e0 + a) * 128 + d0 + b2], acc[a][b2]);
}

__global__ __launch_bounds__(256) void cvt_kvT(const float* __restrict__ P,
                                               bf16_t* __restrict__ o) {
  const int i = blockIdx.x * 256 + threadIdx.x;
  o[i] = (bf16_t)P[i];
}

// z[b][h] = 1 / (dot(q[b,h,:], ksum[h,:]) + 1e-6)
__global__ __launch_bounds__(256) void z_kernel(const bf16_t* __restrict__ q,
                                                const float* __restrict__ ksum,
                                                float* __restrict__ z) {
  __shared__ float ks[2048];
  const int t = threadIdx.x;
  for (int i = t; i < 2048; i += 256) ks[i] = ksum[i];
  __syncthreads();
  const int b = blockIdx.x * 16 + (t >> 4);
  const int h = t & 15;
  const bf16_t* qr = q + (long)b * DK + h * 128;
  float s = 0.f;
#pragma unroll
  for (int i = 0; i < 16; ++i) {
    const bf16x8 qq = *(const bf16x8*)&qr[i * 8];
#pragma unroll
    for (int r = 0; r < 8; ++r) s += (float)qq[r] * ks[h * 128 + i * 8 + r];
  }
  z[b * NH + h] = 1.f / (s + 1e-6f);
}

extern "C" void kernel_launch(void* const* d_in, const int* in_sizes, int n_in,
                              void* d_out, int out_size, void* d_ws, size_t ws_size,
                              hipStream_t stream) {
  const float* x    = (const float*)d_in[0];
  const float* Wq   = (const float*)d_in[1];
  const float* Wk   = (const float*)d_in[2];
  const float* Wv   = (const float*)d_in[3];
  const float* Wo   = (const float*)d_in[4];
  const float* bo   = (const float*)d_in[5];
  const float* Wg   = (const float*)d_in[6];
  const float* bg   = (const float*)d_in[7];
  const float* Wout = (const float*)d_in[8];
  const float* bout = (const float*)d_in[9];

  char* ws = (char*)d_ws;
  size_t off = 0;
  auto alloc = [&](size_t bytes) -> void* {
    void* p = ws + off;
    off += (bytes + 255) & ~(size_t)255;
    return p;
  };
  bf16_t* concat = (bf16_t*)alloc((size_t)B_SZ * 4096 * 2);  // [op | x] bf16
  bf16_t* qb     = (bf16_t*)alloc((size_t)B_SZ * DK * 2);
  bf16_t* kb     = (bf16_t*)alloc((size_t)B_SZ * DK * 2);
  bf16_t* vb     = (bf16_t*)alloc((size_t)B_SZ * DV * 2);
  bf16_t* attb   = (bf16_t*)alloc((size_t)B_SZ * DV * 2);
  bf16_t* outb   = (bf16_t*)alloc((size_t)B_SZ * DIN * 2);
  bf16_t* WqT    = (bf16_t*)alloc((size_t)DK * DIN * 2);
  bf16_t* WkT    = (bf16_t*)alloc((size_t)DK * DIN * 2);
  bf16_t* WvT    = (bf16_t*)alloc((size_t)DV * DIN * 2);
  bf16_t* WoT    = (bf16_t*)alloc((size_t)DIN * DV * 2);
  bf16_t* WgT    = (bf16_t*)alloc((size_t)DIN * 4096 * 2);
  bf16_t* WoutT  = (bf16_t*)alloc((size_t)DOUT * DIN * 2);
  float*  P      = (float*)alloc((size_t)NH * 128 * 128 * 4);
  bf16_t* kvT    = (bf16_t*)alloc((size_t)NH * 128 * 128 * 2);
  float*  ksum   = (float*)alloc((size_t)DK * 4);
  float*  zbuf   = (float*)alloc((size_t)B_SZ * NH * 4);

  hipMemsetAsync(P, 0, (size_t)NH * 128 * 128 * 4, stream);
  hipMemsetAsync(ksum, 0, (size_t)DK * 4, stream);

  cvt_x_kernel<<<(B_SZ * DIN) / 1024, 256, 0, stream>>>(x, concat);

  const dim3 tb(32, 8);
  transpose_f32_bf16<<<dim3(64, 64), tb, 0, stream>>>(Wq, WqT, 2048, 2048);
  transpose_f32_bf16<<<dim3(64, 64), tb, 0, stream>>>(Wk, WkT, 2048, 2048);
  transpose_f32_bf16<<<dim3(64, 64), tb, 0, stream>>>(Wv, WvT, 2048, 2048);
  transpose_f32_bf16<<<dim3(64, 64), tb, 0, stream>>>(Wo, WoT, 2048, 2048);
  transpose_f32_bf16<<<dim3(64, 128), tb, 0, stream>>>(Wg, WgT, 4096, 2048);
  transpose_f32_bf16<<<dim3(16, 64), tb, 0, stream>>>(Wout, WoutT, 2048, 512);

  const bf16_t* xb = concat + 2048;  // bf16 x view, lda=4096

  // q/k/v projections
  gemm_bt<1><<<dim3(16, 128, 1), 256, 0, stream>>>(xb, 4096, 0, WqT, 2048, 0, qb, 2048, 0, 2048, nullptr, nullptr);
  gemm_bt<1><<<dim3(16, 128, 1), 256, 0, stream>>>(xb, 4096, 0, WkT, 2048, 0, kb, 2048, 0, 2048, nullptr, nullptr);
  gemm_bt<0><<<dim3(16, 128, 1), 256, 0, stream>>>(xb, 4096, 0, WvT, 2048, 0, vb, 2048, 0, 2048, nullptr, nullptr);

  ksum_kernel<<<dim3(8, 64), 256, 0, stream>>>(kb, ksum);
  kv_kernel<<<dim3(16, 32), 256, 0, stream>>>(kb, vb, P);
  cvt_kvT<<<1024, 256, 0, stream>>>(P, kvT);
  z_kernel<<<B_SZ / 16, 256, 0, stream>>>(qb, ksum, zbuf);

  // att[b, h*128+e] = z[b,h] * sum_d q[b,h*128+d] * kvT[h][e][d]
  gemm_bt<3><<<dim3(1, 128, 16), 256, 0, stream>>>(qb, 2048, 128, kvT, 128, 16384, attb, 2048, 128, 128, nullptr, zbuf);

  // out_proj = att @ Wo + bo  -> concat cols [0, 2048)
  gemm_bt<2><<<dim3(16, 128, 1), 256, 0, stream>>>(attb, 2048, 0, WoT, 2048, 0, concat, 4096, 0, 2048, bo, nullptr);

  // gate GEMM over concat (K=4096), epilogue: sigmoid-mix -> outb
  gemm_bt<4><<<dim3(16, 128, 1), 256, 0, stream>>>(concat, 4096, 0, WgT, 4096, 0, outb, 2048, 0, 4096, bg, x);

  // final: outb @ Wout + bout -> d_out (f32)
  gemm_bt<5><<<dim3(4, 128, 1), 256, 0, stream>>>(outb, 2048, 0, WoutT, 2048, 0, d_out, 512, 0, 2048, bout, nullptr);
}

// Round 2
// 1812.583 us; speedup vs baseline: 1.1066x; 1.1066x over previous
//
#include <hip/hip_runtime.h>
#include <hip/hip_bf16.h>
#include <math.h>

typedef __bf16 bf16_t;
typedef __attribute__((ext_vector_type(8))) __bf16 bf16x8;
typedef __attribute__((ext_vector_type(4))) __bf16 bf16x4;
typedef __attribute__((ext_vector_type(4))) float f32x4;

#define DEVI __device__ __forceinline__

constexpr int B_SZ = 16384, DIN = 2048, DK = 2048, DV = 2048, NH = 16, DOUT = 512;

DEVI void load_lds16(const void* gptr, void* lptr) {
  __builtin_amdgcn_global_load_lds(
      (const __attribute__((address_space(1))) unsigned int*)gptr,
      (__attribute__((address_space(3))) unsigned int*)lptr,
      16, 0, 0);
}

// ---------------------------------------------------------------------------
// Generic bf16 GEMM, B given transposed (Bt[n][k]), C = A @ Bt^T (+ epilogue)
// Tile 128x128, BK=64 (two stacked BK=32 LDS tiles -> one barrier pair / 64-K,
// conflict-free contiguous frag reads preserved). 256 thr = 4 waves, each
// 64x64 via 4x4 of 16x16x32 MFMA. K must be a multiple of 64.
// EPI: 0 plain bf16, 1 qkv (relu+1e-4 for col<4096), 2 +bias bf16,
//      4 sigmoid-gate mix bf16, 5 +bias f32
// ---------------------------------------------------------------------------
template <int EPI>
__global__ __launch_bounds__(256) void gemm_bt(
    const bf16_t* __restrict__ A, int lda, long aZ,
    const bf16_t* __restrict__ Bt, int ldb, long bZ,
    void* __restrict__ Cv, int ldc, long cZ, int K,
    const float* __restrict__ aux1,   // bias
    const float* __restrict__ aux2) { // x (EPI4)
  __shared__ __align__(16) bf16_t As[2][128 * 32];
  __shared__ __align__(16) bf16_t Bs[2][128 * 32];
  const int tid = threadIdx.x;
  const int bn = blockIdx.x, bm = blockIdx.y, bz = blockIdx.z;
  const int lane = tid & 63, w = tid >> 6;
  const int wm = (w & 1) * 64, wn = (w >> 1) * 64;
  const int ln = lane & 15, qd = lane >> 4;

  const bf16_t* Ab = A + (long)bm * 128 * lda + (long)bz * aZ;
  const bf16_t* Bb = Bt + (long)bn * 128 * ldb + (long)bz * bZ;

  const int srow = tid >> 2, scol = (tid & 3) * 8;  // 64 rows x 32 k per issue

  f32x4 acc[4][4] = {};

  for (int k0 = 0; k0 < K; k0 += 64) {
#pragma unroll
    for (int kk = 0; kk < 2; ++kk) {
#pragma unroll
      for (int it = 0; it < 2; ++it) {
        load_lds16(Ab + (long)(srow + it * 64) * lda + k0 + kk * 32 + scol,
                   &As[kk][it * 2048 + tid * 8]);
        load_lds16(Bb + (long)(srow + it * 64) * ldb + k0 + kk * 32 + scol,
                   &Bs[kk][it * 2048 + tid * 8]);
      }
    }
    __syncthreads();
#pragma unroll
    for (int s = 0; s < 2; ++s) {
      bf16x8 af[4], bfr[4];
#pragma unroll
      for (int i = 0; i < 4; ++i)
        af[i] = *(const bf16x8*)&As[s][(wm + i * 16 + ln) * 32 + qd * 8];
#pragma unroll
      for (int j = 0; j < 4; ++j)
        bfr[j] = *(const bf16x8*)&Bs[s][(wn + j * 16 + ln) * 32 + qd * 8];
#pragma unroll
      for (int i = 0; i < 4; ++i)
#pragma unroll
        for (int j = 0; j < 4; ++j)
          acc[i][j] = __builtin_amdgcn_mfma_f32_16x16x32_bf16(af[i], bfr[j], acc[i][j], 0, 0, 0);
    }
    __syncthreads();
  }

#pragma unroll
  for (int i = 0; i < 4; ++i) {
#pragma unroll
    for (int j = 0; j < 4; ++j) {
#pragma unroll
      for (int r = 0; r < 4; ++r) {
        const int row = bm * 128 + wm + i * 16 + qd * 4 + r;
        const int col = bn * 128 + wn + j * 16 + ln;
        const long cidx = (long)row * ldc + (long)bz * cZ + col;
        float val = acc[i][j][r];
        if (EPI == 0) {
          ((bf16_t*)Cv)[cidx] = (bf16_t)val;
        } else if (EPI == 1) {
          if (col < 4096) val = fmaxf(val, 0.f) + 1e-4f;  // q,k feat; v plain
          ((bf16_t*)Cv)[cidx] = (bf16_t)val;
        } else if (EPI == 2) {
          val += aux1[col];
          ((bf16_t*)Cv)[cidx] = (bf16_t)val;
        } else if (EPI == 4) {
          const float g = 1.f / (1.f + __expf(-(val + aux1[col])));
          const float op = (float)A[(long)row * lda + col];  // concat cols [0,2048)
          const float xx = aux2[(long)row * DIN + col];
          ((bf16_t*)Cv)[cidx] = (bf16_t)(g * op + (1.f - g) * xx);
        } else if (EPI == 5) {
          ((float*)Cv)[cidx] = val + aux1[col];
        }
      }
    }
  }
}

// x f32 -> bf16 into concat buffer cols [2048, 4096)
__global__ __launch_bounds__(256) void cvt_x_kernel(const float* __restrict__ x,
                                                    bf16_t* __restrict__ cc) {
  const long i = ((long)blockIdx.x * 256 + threadIdx.x) * 4;
  const long row = i >> 11;
  const int col = (int)(i & 2047);
  const float4 f = *(const float4*)&x[i];
  bf16x4 o;
  o[0] = (bf16_t)f.x; o[1] = (bf16_t)f.y; o[2] = (bf16_t)f.z; o[3] = (bf16_t)f.w;
  *(bf16x4*)&cc[row * 4096 + 2048 + col] = o;
}

// W [R][C] f32 -> Wt [C][R] bf16
__global__ __launch_bounds__(256) void transpose_f32_bf16(const float* __restrict__ in,
                                                          bf16_t* __restrict__ out,
                                                          int R, int C) {
  __shared__ bf16_t tile[32][33];
  const int c0 = blockIdx.x * 32, r0 = blockIdx.y * 32;
  for (int i = threadIdx.y; i < 32; i += 8)
    tile[i][threadIdx.x] = (bf16_t)in[(long)(r0 + i) * C + c0 + threadIdx.x];
  __syncthreads();
  for (int i = threadIdx.y; i < 32; i += 8)
    out[(long)(c0 + i) * R + r0 + threadIdx.x] = tile[threadIdx.x][i];
}

// ksum[c] = sum_b k[b][c]   (k = qkv cols [2048,4096), ld 6144)
__global__ __launch_bounds__(256) void ksum_kernel(const bf16_t* __restrict__ qkv,
                                                   float* __restrict__ ksum) {
  const int col = blockIdx.x * 256 + threadIdx.x;
  const int r0 = blockIdx.y * 256;
  const bf16_t* k = qkv + 2048;
  float s = 0.f;
  for (int r = 0; r < 256; ++r) s += (float)k[(long)(r0 + r) * 6144 + col];
  atomicAdd(&ksum[col], s);
}

// P[h][d][e] += sum_b k[b, h*128+d] * v[b, h*128+e]
__global__ __launch_bounds__(256) void kv_kernel(const bf16_t* __restrict__ qkv,
                                                 float* __restrict__ P) {
  const int h = blockIdx.x, sp = blockIdx.y;
  const int t = threadIdx.x;
  __shared__ __align__(16) bf16_t kS[64 * 128];
  __shared__ __align__(16) bf16_t vS[64 * 128];
  const int d0 = (t >> 4) * 8, e0 = (t & 15) * 8;
  const int srow = t >> 4, scol = (t & 15) * 8;
  float acc[8][8] = {};
  const bf16_t* kp = qkv + 2048 + h * 128;
  const bf16_t* vp = qkv + 4096 + h * 128;
  const long base = (long)sp * 512 * 6144;
  for (int c0 = 0; c0 < 512; c0 += 64) {
#pragma unroll
    for (int it = 0; it < 4; ++it) {
      load_lds16(kp + base + (long)(c0 + it * 16 + srow) * 6144 + scol, &kS[it * 2048 + t * 8]);
      load_lds16(vp + base + (long)(c0 + it * 16 + srow) * 6144 + scol, &vS[it * 2048 + t * 8]);
    }
    __syncthreads();
    for (int bb = 0; bb < 64; ++bb) {
      const bf16x8 kk = *(const bf16x8*)&kS[bb * 128 + d0];
      const bf16x8 vv = *(const bf16x8*)&vS[bb * 128 + e0];
      float kf[8], vf[8];
#pragma unroll
      for (int r = 0; r < 8; ++r) { kf[r] = (float)kk[r]; vf[r] = (float)vv[r]; }
#pragma unroll
      for (int a = 0; a < 8; ++a)
#pragma unroll
        for (int b2 = 0; b2 < 8; ++b2) acc[a][b2] += kf[a] * vf[b2];
    }
    __syncthreads();
  }
  float* Ph = P + (long)h * 16384;
#pragma unroll
  for (int a = 0; a < 8; ++a)
#pragma unroll
    for (int b2 = 0; b2 < 8; ++b2)
      atomicAdd(&Ph[(d0 + a) * 128 + e0 + b2], acc[a][b2]);
}

__global__ __launch_bounds__(256) void cvt_bf(const float* __restrict__ P,
                                              bf16_t* __restrict__ o, int n) {
  const int i = blockIdx.x * 256 + threadIdx.x;
  if (i < n) o[i] = (bf16_t)P[i];
}

// z[b][h] = 1 / (dot(q[b,h,:], ksum[h,:]) + 1e-6); then q *= z in-place
__global__ __launch_bounds__(256) void z_kernel(bf16_t* __restrict__ qkv,
                                                const float* __restrict__ ksum) {
  __shared__ float ks[2048];
  const int t = threadIdx.x;
  for (int i = t; i < 2048; i += 256) ks[i] = ksum[i];
  __syncthreads();
  const int b = blockIdx.x * 16 + (t >> 4);
  const int h = t & 15;
  bf16_t* qr = qkv + (long)b * 6144 + h * 128;
  bf16x8 qq[16];
  float s = 0.f;
#pragma unroll
  for (int i = 0; i < 16; ++i) {
    qq[i] = *(const bf16x8*)&qr[i * 8];
#pragma unroll
    for (int r = 0; r < 8; ++r) s += (float)qq[i][r] * ks[h * 128 + i * 8 + r];
  }
  const float z = 1.f / (s + 1e-6f);
#pragma unroll
  for (int i = 0; i < 16; ++i) {
#pragma unroll
    for (int r = 0; r < 8; ++r) qq[i][r] = (bf16_t)((float)qq[i][r] * z);
    *(bf16x8*)&qr[i * 8] = qq[i];
  }
}

extern "C" void kernel_launch(void* const* d_in, const int* in_sizes, int n_in,
                              void* d_out, int out_size, void* d_ws, size_t ws_size,
                              hipStream_t stream) {
  const float* x    = (const float*)d_in[0];
  const float* Wq   = (const float*)d_in[1];
  const float* Wk   = (const float*)d_in[2];
  const float* Wv   = (const float*)d_in[3];
  const float* Wo   = (const float*)d_in[4];
  const float* bo   = (const float*)d_in[5];
  const float* Wg   = (const float*)d_in[6];
  const float* bg   = (const float*)d_in[7];
  const float* Wout = (const float*)d_in[8];
  const float* bout = (const float*)d_in[9];

  char* ws = (char*)d_ws;
  size_t off = 0;
  auto alloc = [&](size_t bytes) -> void* {
    void* p = ws + off;
    off += (bytes + 255) & ~(size_t)255;
    return p;
  };
  bf16_t* concat = (bf16_t*)alloc((size_t)B_SZ * 4096 * 2);   // [op | x] bf16
  bf16_t* qkv    = (bf16_t*)alloc((size_t)B_SZ * 6144 * 2);   // [q | k | v]
  bf16_t* outb   = (bf16_t*)alloc((size_t)B_SZ * DIN * 2);
  bf16_t* WqkvT  = (bf16_t*)alloc((size_t)6144 * DIN * 2);
  bf16_t* WoT    = (bf16_t*)alloc((size_t)DIN * DV * 2);
  bf16_t* WgT    = (bf16_t*)alloc((size_t)DIN * 4096 * 2);
  bf16_t* WoutT  = (bf16_t*)alloc((size_t)DOUT * DIN * 2);
  float*  P      = (float*)alloc((size_t)NH * 128 * 128 * 4);
  bf16_t* kvbf   = (bf16_t*)alloc((size_t)NH * 128 * 128 * 2);
  bf16_t* G      = (bf16_t*)alloc((size_t)DIN * DK * 2);      // (blockdiag(kv) @ Wo)^T
  float*  ksum   = (float*)alloc((size_t)DK * 4);

  hipMemsetAsync(P, 0, (size_t)NH * 128 * 128 * 4, stream);
  hipMemsetAsync(ksum, 0, (size_t)DK * 4, stream);

  cvt_x_kernel<<<(B_SZ * DIN) / 1024, 256, 0, stream>>>(x, concat);

  const dim3 tb(32, 8);
  transpose_f32_bf16<<<dim3(64, 64), tb, 0, stream>>>(Wq, WqkvT, 2048, 2048);
  transpose_f32_bf16<<<dim3(64, 64), tb, 0, stream>>>(Wk, WqkvT + (size_t)2048 * 2048, 2048, 2048);
  transpose_f32_bf16<<<dim3(64, 64), tb, 0, stream>>>(Wv, WqkvT + (size_t)4096 * 2048, 2048, 2048);
  transpose_f32_bf16<<<dim3(64, 64), tb, 0, stream>>>(Wo, WoT, 2048, 2048);
  transpose_f32_bf16<<<dim3(64, 128), tb, 0, stream>>>(Wg, WgT, 4096, 2048);
  transpose_f32_bf16<<<dim3(16, 64), tb, 0, stream>>>(Wout, WoutT, 2048, 512);

  const bf16_t* xb = concat + 2048;  // bf16 x view, lda=4096

  // fused q|k|v projection: [B,2048] @ [2048,6144] -> qkv, relu-feat on q,k
  gemm_bt<1><<<dim3(48, 128, 1), 256, 0, stream>>>(xb, 4096, 0, WqkvT, 2048, 0,
                                                   qkv, 6144, 0, 2048, nullptr, nullptr);

  ksum_kernel<<<dim3(8, 64), 256, 0, stream>>>(qkv, ksum);
  kv_kernel<<<dim3(16, 32), 256, 0, stream>>>(qkv, P);
  cvt_bf<<<1024, 256, 0, stream>>>(P, kvbf, NH * 128 * 128);
  z_kernel<<<B_SZ / 16, 256, 0, stream>>>(qkv, ksum);  // also scales q by z

  // G[j][h*128+d] = sum_e kv_h[d][e] * WoT[j][h*128+e]  (per-head kv@Wo, transposed)
  gemm_bt<0><<<dim3(1, 16, 16), 256, 0, stream>>>(WoT, 2048, 128, kvbf, 128, 16384,
                                                  G, 2048, 128, 128, nullptr, nullptr);

  // out_proj = qz @ G^T + bo -> concat cols [0,2048)
  gemm_bt<2><<<dim3(16, 128, 1), 256, 0, stream>>>(qkv, 6144, 0, G, 2048, 0,
                                                   concat, 4096, 0, 2048, bo, nullptr);

  // gate GEMM over concat (K=4096), epilogue: sigmoid-mix -> outb
  gemm_bt<4><<<dim3(16, 128, 1), 256, 0, stream>>>(concat, 4096, 0, WgT, 4096, 0,
                                                   outb, 2048, 0, 4096, bg, x);

  // final: outb @ Wout + bout -> d_out (f32)
  gemm_bt<5><<<dim3(4, 128, 1), 256, 0, stream>>>(outb, 2048, 0, WoutT, 2048, 0,
                                                  d_out, 512, 0, 2048, bout, nullptr);
}

// Round 3
// 1776.181 us; speedup vs baseline: 1.1292x; 1.0205x over previous
//
#include <hip/hip_runtime.h>
#include <hip/hip_bf16.h>
#include <math.h>

typedef __bf16 bf16_t;
typedef __attribute__((ext_vector_type(8))) __bf16 bf16x8;
typedef __attribute__((ext_vector_type(4))) __bf16 bf16x4;
typedef __attribute__((ext_vector_type(4))) float f32x4;
typedef __attribute__((ext_vector_type(16))) float f32x16;

#define DEVI __device__ __forceinline__

constexpr int B_SZ = 16384, DIN = 2048, DK = 2048, DV = 2048, NH = 16, DOUT = 512;

DEVI void load_lds16(const void* gptr, void* lptr) {
  __builtin_amdgcn_global_load_lds(
      (const __attribute__((address_space(1))) unsigned int*)gptr,
      (__attribute__((address_space(3))) unsigned int*)lptr,
      16, 0, 0);
}

// ---------------------------------------------------------------------------
// bf16 GEMM, B transposed (Bt[n][k]), C = A @ Bt^T (+ epilogue)
// Tile 128x128, BK=64 (two BK=32 LDS sub-tiles), 256 thr = 4 waves, each wave
// 64x64 via 2x2 of mfma_f32_32x32x16_bf16 x 4 k-segments.
// LDS XOR swizzle: 16B granule g holds global colgroup (g&3)^((row>>1)&3);
// read-side banks cycle 0,4,1,5,2,6,3,7 -> 2-way only (free).
// EPI: 0 plain bf16, 1 qkv (relu+1e-4 for col<4096), 2 +bias bf16,
//      4 sigmoid-gate mix bf16, 5 +bias f32
// ---------------------------------------------------------------------------
template <int EPI>
__global__ __launch_bounds__(256) void gemm_bt(
    const bf16_t* __restrict__ A, int lda, long aZ,
    const bf16_t* __restrict__ Bt, int ldb, long bZ,
    void* __restrict__ Cv, int ldc, long cZ, int K,
    const float* __restrict__ aux1,   // bias
    const float* __restrict__ aux2) { // x (EPI4)
  __shared__ __align__(16) bf16_t As[2][128 * 32];
  __shared__ __align__(16) bf16_t Bs[2][128 * 32];
  const int tid = threadIdx.x;
  const int bn = blockIdx.x, bm = blockIdx.y, bz = blockIdx.z;
  const int lane = tid & 63, w = tid >> 6;
  const int wm = (w & 1) * 64, wn = (w >> 1) * 64;
  const int lm = lane & 31, lh = lane >> 5;  // row-in-32, k-half

  const bf16_t* Ab = A + (long)bm * 128 * lda + (long)bz * aZ;
  const bf16_t* Bb = Bt + (long)bn * 128 * ldb + (long)bz * bZ;

  // staging: granule g=tid -> row g>>2, global colgroup (g&3)^((g>>3)&3)
  const int srow = tid >> 2;
  const int scol = ((tid & 3) ^ ((tid >> 3) & 3)) * 8;

  f32x16 acc[2][2] = {};

  for (int k0 = 0; k0 < K; k0 += 64) {
#pragma unroll
    for (int kk = 0; kk < 2; ++kk) {
#pragma unroll
      for (int it = 0; it < 2; ++it) {
        load_lds16(Ab + (long)(srow + it * 64) * lda + k0 + kk * 32 + scol,
                   &As[kk][it * 2048 + tid * 8]);
        load_lds16(Bb + (long)(srow + it * 64) * ldb + k0 + kk * 32 + scol,
                   &Bs[kk][it * 2048 + tid * 8]);
      }
    }
    __syncthreads();
#pragma unroll
    for (int s = 0; s < 4; ++s) {
      const int kk = s >> 1;
      const int cg = (s & 1) * 2 + lh;  // 16B colgroup within BK=32 row
      bf16x8 af[2], bfr[2];
#pragma unroll
      for (int i = 0; i < 2; ++i) {
        const int R = wm + i * 32 + lm;
        af[i] = *(const bf16x8*)&As[kk][R * 32 + ((cg ^ ((R >> 1) & 3)) * 8)];
      }
#pragma unroll
      for (int j = 0; j < 2; ++j) {
        const int R = wn + j * 32 + lm;
        bfr[j] = *(const bf16x8*)&Bs[kk][R * 32 + ((cg ^ ((R >> 1) & 3)) * 8)];
      }
#pragma unroll
      for (int i = 0; i < 2; ++i)
#pragma unroll
        for (int j = 0; j < 2; ++j)
          acc[i][j] = __builtin_amdgcn_mfma_f32_32x32x16_bf16(af[i], bfr[j], acc[i][j], 0, 0, 0);
    }
    __syncthreads();
  }

  // C/D: col = lane&31, row = (reg&3) + 8*(reg>>2) + 4*(lane>>5)
#pragma unroll
  for (int i = 0; i < 2; ++i) {
#pragma unroll
    for (int j = 0; j < 2; ++j) {
      const int col = bn * 128 + wn + j * 32 + lm;
#pragma unroll
      for (int r = 0; r < 16; ++r) {
        const int row = bm * 128 + wm + i * 32 + (r & 3) + 8 * (r >> 2) + 4 * lh;
        const long cidx = (long)row * ldc + (long)bz * cZ + col;
        float val = acc[i][j][r];
        if (EPI == 0) {
          ((bf16_t*)Cv)[cidx] = (bf16_t)val;
        } else if (EPI == 1) {
          if (col < 4096) val = fmaxf(val, 0.f) + 1e-4f;  // q,k feat; v plain
          ((bf16_t*)Cv)[cidx] = (bf16_t)val;
        } else if (EPI == 2) {
          val += aux1[col];
          ((bf16_t*)Cv)[cidx] = (bf16_t)val;
        } else if (EPI == 4) {
          const float g = 1.f / (1.f + __expf(-(val + aux1[col])));
          const float op = (float)A[(long)row * lda + col];  // concat cols [0,2048)
          const float xx = aux2[(long)row * DIN + col];
          ((bf16_t*)Cv)[cidx] = (bf16_t)(g * op + (1.f - g) * xx);
        } else if (EPI == 5) {
          ((float*)Cv)[cidx] = val + aux1[col];
        }
      }
    }
  }
}

// x f32 -> bf16 into concat buffer cols [2048, 4096)
__global__ __launch_bounds__(256) void cvt_x_kernel(const float* __restrict__ x,
                                                    bf16_t* __restrict__ cc) {
  const long i = ((long)blockIdx.x * 256 + threadIdx.x) * 4;
  const long row = i >> 11;
  const int col = (int)(i & 2047);
  const float4 f = *(const float4*)&x[i];
  bf16x4 o;
  o[0] = (bf16_t)f.x; o[1] = (bf16_t)f.y; o[2] = (bf16_t)f.z; o[3] = (bf16_t)f.w;
  *(bf16x4*)&cc[row * 4096 + 2048 + col] = o;
}

// W [R][C] f32 -> Wt [C][R] bf16
__global__ __launch_bounds__(256) void transpose_f32_bf16(const float* __restrict__ in,
                                                          bf16_t* __restrict__ out,
                                                          int R, int C) {
  __shared__ bf16_t tile[32][33];
  const int c0 = blockIdx.x * 32, r0 = blockIdx.y * 32;
  for (int i = threadIdx.y; i < 32; i += 8)
    tile[i][threadIdx.x] = (bf16_t)in[(long)(r0 + i) * C + c0 + threadIdx.x];
  __syncthreads();
  for (int i = threadIdx.y; i < 32; i += 8)
    out[(long)(c0 + i) * R + r0 + threadIdx.x] = tile[threadIdx.x][i];
}

// ksum[c] = sum_b k[b][c]   (k = qkv cols [2048,4096), ld 6144)
__global__ __launch_bounds__(256) void ksum_kernel(const bf16_t* __restrict__ qkv,
                                                   float* __restrict__ ksum) {
  const int col = blockIdx.x * 256 + threadIdx.x;
  const int r0 = blockIdx.y * 256;
  const bf16_t* k = qkv + 2048;
  float s = 0.f;
  for (int r = 0; r < 256; ++r) s += (float)k[(long)(r0 + r) * 6144 + col];
  atomicAdd(&ksum[col], s);
}

// P[h][d][e] += sum_b k[b, h*128+d] * v[b, h*128+e]
__global__ __launch_bounds__(256) void kv_kernel(const bf16_t* __restrict__ qkv,
                                                 float* __restrict__ P) {
  const int h = blockIdx.x, sp = blockIdx.y;
  const int t = threadIdx.x;
  __shared__ __align__(16) bf16_t kS[64 * 128];
  __shared__ __align__(16) bf16_t vS[64 * 128];
  const int d0 = (t >> 4) * 8, e0 = (t & 15) * 8;
  const int srow = t >> 4, scol = (t & 15) * 8;
  float acc[8][8] = {};
  const bf16_t* kp = qkv + 2048 + h * 128;
  const bf16_t* vp = qkv + 4096 + h * 128;
  const long base = (long)sp * 512 * 6144;
  for (int c0 = 0; c0 < 512; c0 += 64) {
#pragma unroll
    for (int it = 0; it < 4; ++it) {
      load_lds16(kp + base + (long)(c0 + it * 16 + srow) * 6144 + scol, &kS[it * 2048 + t * 8]);
      load_lds16(vp + base + (long)(c0 + it * 16 + srow) * 6144 + scol, &vS[it * 2048 + t * 8]);
    }
    __syncthreads();
    for (int bb = 0; bb < 64; ++bb) {
      const bf16x8 kk = *(const bf16x8*)&kS[bb * 128 + d0];
      const bf16x8 vv = *(const bf16x8*)&vS[bb * 128 + e0];
      float kf[8], vf[8];
#pragma unroll
      for (int r = 0; r < 8; ++r) { kf[r] = (float)kk[r]; vf[r] = (float)vv[r]; }
#pragma unroll
      for (int a = 0; a < 8; ++a)
#pragma unroll
        for (int b2 = 0; b2 < 8; ++b2) acc[a][b2] += kf[a] * vf[b2];
    }
    __syncthreads();
  }
  float* Ph = P + (long)h * 16384;
#pragma unroll
  for (int a = 0; a < 8; ++a)
#pragma unroll
    for (int b2 = 0; b2 < 8; ++b2)
      atomicAdd(&Ph[(d0 + a) * 128 + e0 + b2], acc[a][b2]);
}

__global__ __launch_bounds__(256) void cvt_bf(const float* __restrict__ P,
                                              bf16_t* __restrict__ o, int n) {
  const int i = blockIdx.x * 256 + threadIdx.x;
  if (i < n) o[i] = (bf16_t)P[i];
}

// z[b][h] = 1 / (dot(q[b,h,:], ksum[h,:]) + 1e-6); then q *= z in-place
__global__ __launch_bounds__(256) void z_kernel(bf16_t* __restrict__ qkv,
                                                const float* __restrict__ ksum) {
  __shared__ float ks[2048];
  const int t = threadIdx.x;
  for (int i = t; i < 2048; i += 256) ks[i] = ksum[i];
  __syncthreads();
  const int b = blockIdx.x * 16 + (t >> 4);
  const int h = t & 15;
  bf16_t* qr = qkv + (long)b * 6144 + h * 128;
  bf16x8 qq[16];
  float s = 0.f;
#pragma unroll
  for (int i = 0; i < 16; ++i) {
    qq[i] = *(const bf16x8*)&qr[i * 8];
#pragma unroll
    for (int r = 0; r < 8; ++r) s += (float)qq[i][r] * ks[h * 128 + i * 8 + r];
  }
  const float z = 1.f / (s + 1e-6f);
#pragma unroll
  for (int i = 0; i < 16; ++i) {
#pragma unroll
    for (int r = 0; r < 8; ++r) qq[i][r] = (bf16_t)((float)qq[i][r] * z);
    *(bf16x8*)&qr[i * 8] = qq[i];
  }
}

extern "C" void kernel_launch(void* const* d_in, const int* in_sizes, int n_in,
                              void* d_out, int out_size, void* d_ws, size_t ws_size,
                              hipStream_t stream) {
  const float* x    = (const float*)d_in[0];
  const float* Wq   = (const float*)d_in[1];
  const float* Wk   = (const float*)d_in[2];
  const float* Wv   = (const float*)d_in[3];
  const float* Wo   = (const float*)d_in[4];
  const float* bo   = (const float*)d_in[5];
  const float* Wg   = (const float*)d_in[6];
  const float* bg   = (const float*)d_in[7];
  const float* Wout = (const float*)d_in[8];
  const float* bout = (const float*)d_in[9];

  char* ws = (char*)d_ws;
  size_t off = 0;
  auto alloc = [&](size_t bytes) -> void* {
    void* p = ws + off;
    off += (bytes + 255) & ~(size_t)255;
    return p;
  };
  bf16_t* concat = (bf16_t*)alloc((size_t)B_SZ * 4096 * 2);   // [op | x] bf16
  bf16_t* qkv    = (bf16_t*)alloc((size_t)B_SZ * 6144 * 2);   // [q | k | v]
  bf16_t* outb   = (bf16_t*)alloc((size_t)B_SZ * DIN * 2);
  bf16_t* WqkvT  = (bf16_t*)alloc((size_t)6144 * DIN * 2);
  bf16_t* WoT    = (bf16_t*)alloc((size_t)DIN * DV * 2);
  bf16_t* WgT    = (bf16_t*)alloc((size_t)DIN * 4096 * 2);
  bf16_t* WoutT  = (bf16_t*)alloc((size_t)DOUT * DIN * 2);
  float*  P      = (float*)alloc((size_t)NH * 128 * 128 * 4);
  bf16_t* kvbf   = (bf16_t*)alloc((size_t)NH * 128 * 128 * 2);
  bf16_t* G      = (bf16_t*)alloc((size_t)DIN * DK * 2);      // (blockdiag(kv) @ Wo)^T
  float*  ksum   = (float*)alloc((size_t)DK * 4);

  hipMemsetAsync(P, 0, (size_t)NH * 128 * 128 * 4, stream);
  hipMemsetAsync(ksum, 0, (size_t)DK * 4, stream);

  cvt_x_kernel<<<(B_SZ * DIN) / 1024, 256, 0, stream>>>(x, concat);

  const dim3 tb(32, 8);
  transpose_f32_bf16<<<dim3(64, 64), tb, 0, stream>>>(Wq, WqkvT, 2048, 2048);
  transpose_f32_bf16<<<dim3(64, 64), tb, 0, stream>>>(Wk, WqkvT + (size_t)2048 * 2048, 2048, 2048);
  transpose_f32_bf16<<<dim3(64, 64), tb, 0, stream>>>(Wv, WqkvT + (size_t)4096 * 2048, 2048, 2048);
  transpose_f32_bf16<<<dim3(64, 64), tb, 0, stream>>>(Wo, WoT, 2048, 2048);
  transpose_f32_bf16<<<dim3(64, 128), tb, 0, stream>>>(Wg, WgT, 4096, 2048);
  transpose_f32_bf16<<<dim3(16, 64), tb, 0, stream>>>(Wout, WoutT, 2048, 512);

  const bf16_t* xb = concat + 2048;  // bf16 x view, lda=4096

  // fused q|k|v projection: [B,2048] @ [2048,6144] -> qkv, relu-feat on q,k
  gemm_bt<1><<<dim3(48, 128, 1), 256, 0, stream>>>(xb, 4096, 0, WqkvT, 2048, 0,
                                                   qkv, 6144, 0, 2048, nullptr, nullptr);

  ksum_kernel<<<dim3(8, 64), 256, 0, stream>>>(qkv, ksum);
  kv_kernel<<<dim3(16, 32), 256, 0, stream>>>(qkv, P);
  cvt_bf<<<1024, 256, 0, stream>>>(P, kvbf, NH * 128 * 128);
  z_kernel<<<B_SZ / 16, 256, 0, stream>>>(qkv, ksum);  // also scales q by z

  // G[j][h*128+d] = sum_e kv_h[d][e] * WoT[j][h*128+e]  (per-head kv@Wo, transposed)
  gemm_bt<0><<<dim3(1, 16, 16), 256, 0, stream>>>(WoT, 2048, 128, kvbf, 128, 16384,
                                                  G, 2048, 128, 128, nullptr, nullptr);

  // out_proj = qz @ G^T + bo -> concat cols [0,2048)
  gemm_bt<2><<<dim3(16, 128, 1), 256, 0, stream>>>(qkv, 6144, 0, G, 2048, 0,
                                                   concat, 4096, 0, 2048, bo, nullptr);

  // gate GEMM over concat (K=4096), epilogue: sigmoid-mix -> outb
  gemm_bt<4><<<dim3(16, 128, 1), 256, 0, stream>>>(concat, 4096, 0, WgT, 4096, 0,
                                                   outb, 2048, 0, 4096, bg, x);

  // final: outb @ Wout + bout -> d_out (f32)
  gemm_bt<5><<<dim3(4, 128, 1), 256, 0, stream>>>(outb, 2048, 0, WoutT, 2048, 0,
                                                  d_out, 512, 0, 2048, bout, nullptr);
}

// Round 4
// 1728.920 us; speedup vs baseline: 1.1601x; 1.0273x over previous
//
#include <hip/hip_runtime.h>
#include <hip/hip_bf16.h>
#include <math.h>

typedef __bf16 bf16_t;
typedef __attribute__((ext_vector_type(8))) __bf16 bf16x8;
typedef __attribute__((ext_vector_type(4))) __bf16 bf16x4;
typedef __attribute__((ext_vector_type(16))) float f32x16;

#define DEVI __device__ __forceinline__

constexpr int B_SZ = 16384, DIN = 2048, DK = 2048, DV = 2048, NH = 16, DOUT = 512;

DEVI void load_lds16(const void* gptr, void* lptr) {
  __builtin_amdgcn_global_load_lds(
      (const __attribute__((address_space(1))) unsigned int*)gptr,
      (__attribute__((address_space(3))) unsigned int*)lptr,
      16, 0, 0);
}

// ---------------------------------------------------------------------------
// bf16 GEMM, B transposed (Bt[n][k]), C = A @ Bt^T (+ epilogue)
// Tile 128x128, BK=64 (two BK=32 LDS sub-tiles), 256 thr = 4 waves, each wave
// 64x64 via 2x2 of mfma_f32_32x32x16_bf16 x 4 k-segments.
// __launch_bounds__(256,4): cap regs at 128 (64 AGPR acc + ~50 VGPR) so
// 4 blocks/CU co-reside (vs 3 at 140 regs) -> 4th stream covers barrier drain.
// EPI: 0 plain bf16, 1 qkv (relu+1e-4 for col<4096), 2 +bias bf16,
//      4 sigmoid-gate mix bf16, 5 +bias f32
// ---------------------------------------------------------------------------
template <int EPI>
__global__ __launch_bounds__(256, 4) void gemm_bt(
    const bf16_t* __restrict__ A, int lda, long aZ,
    const bf16_t* __restrict__ Bt, int ldb, long bZ,
    void* __restrict__ Cv, int ldc, long cZ, int K,
    const float* __restrict__ aux1,   // bias
    const float* __restrict__ aux2) { // x (EPI4)
  __shared__ __align__(16) bf16_t As[2][128 * 32];
  __shared__ __align__(16) bf16_t Bs[2][128 * 32];
  const int tid = threadIdx.x;
  const int bn = blockIdx.x, bm = blockIdx.y, bz = blockIdx.z;
  const int lane = tid & 63, w = tid >> 6;
  const int wm = (w & 1) * 64, wn = (w >> 1) * 64;
  const int lm = lane & 31, lh = lane >> 5;  // row-in-32, k-half

  const bf16_t* __restrict__ Ab = A + (long)bm * 128 * lda + (long)bz * aZ;
  const bf16_t* __restrict__ Bb = Bt + (long)bn * 128 * ldb + (long)bz * bZ;

  // staging: granule g=tid -> row g>>2, colgroup g&3 (contiguous, coalesced)
  const int srow = tid >> 2, scol = (tid & 3) * 8;
  const long aRow = (long)srow * lda + scol;
  const long bRow = (long)srow * ldb + scol;

  // LDS read bases (bytes): row stride 64 B, k-half lh picks 16 B
  const char* aBase = (const char*)As + (wm + lm) * 64 + lh * 16;
  const char* bBase = (const char*)Bs + (wn + lm) * 64 + lh * 16;

  f32x16 acc[2][2] = {};

  for (int k0 = 0; k0 < K; k0 += 64) {
    const bf16_t* ap = Ab + aRow + k0;
    const bf16_t* bp = Bb + bRow + k0;
    load_lds16(ap, &As[0][tid * 8]);
    load_lds16(ap + (long)64 * lda, &As[0][2048 + tid * 8]);
    load_lds16(ap + 32, &As[1][tid * 8]);
    load_lds16(ap + (long)64 * lda + 32, &As[1][2048 + tid * 8]);
    load_lds16(bp, &Bs[0][tid * 8]);
    load_lds16(bp + (long)64 * ldb, &Bs[0][2048 + tid * 8]);
    load_lds16(bp + 32, &Bs[1][tid * 8]);
    load_lds16(bp + (long)64 * ldb + 32, &Bs[1][2048 + tid * 8]);
    __syncthreads();
#pragma unroll
    for (int s = 0; s < 4; ++s) {
      const int off = (s >> 1) * 8192 + (s & 1) * 32;
      const bf16x8 af0 = *(const bf16x8*)(aBase + off);
      const bf16x8 af1 = *(const bf16x8*)(aBase + off + 2048);
      const bf16x8 bf0 = *(const bf16x8*)(bBase + off);
      const bf16x8 bf1 = *(const bf16x8*)(bBase + off + 2048);
      acc[0][0] = __builtin_amdgcn_mfma_f32_32x32x16_bf16(af0, bf0, acc[0][0], 0, 0, 0);
      acc[0][1] = __builtin_amdgcn_mfma_f32_32x32x16_bf16(af0, bf1, acc[0][1], 0, 0, 0);
      acc[1][0] = __builtin_amdgcn_mfma_f32_32x32x16_bf16(af1, bf0, acc[1][0], 0, 0, 0);
      acc[1][1] = __builtin_amdgcn_mfma_f32_32x32x16_bf16(af1, bf1, acc[1][1], 0, 0, 0);
    }
    __syncthreads();
  }

  // C/D: col = lane&31, row = (reg&3) + 8*(reg>>2) + 4*(lane>>5)
#pragma unroll
  for (int i = 0; i < 2; ++i) {
#pragma unroll
    for (int j = 0; j < 2; ++j) {
      const int col = bn * 128 + wn + j * 32 + lm;
#pragma unroll
      for (int r = 0; r < 16; ++r) {
        const int row = bm * 128 + wm + i * 32 + (r & 3) + 8 * (r >> 2) + 4 * lh;
        const long cidx = (long)row * ldc + (long)bz * cZ + col;
        float val = acc[i][j][r];
        if (EPI == 0) {
          ((bf16_t*)Cv)[cidx] = (bf16_t)val;
        } else if (EPI == 1) {
          if (col < 4096) val = fmaxf(val, 0.f) + 1e-4f;  // q,k feat; v plain
          ((bf16_t*)Cv)[cidx] = (bf16_t)val;
        } else if (EPI == 2) {
          val += aux1[col];
          ((bf16_t*)Cv)[cidx] = (bf16_t)val;
        } else if (EPI == 4) {
          const float g = 1.f / (1.f + __expf(-(val + aux1[col])));
          const float op = (float)A[(long)row * lda + col];  // concat cols [0,2048)
          const float xx = aux2[(long)row * DIN + col];
          ((bf16_t*)Cv)[cidx] = (bf16_t)(g * op + (1.f - g) * xx);
        } else if (EPI == 5) {
          ((float*)Cv)[cidx] = val + aux1[col];
        }
      }
    }
  }
}

// ---------------------------------------------------------------------------
// Fused prep: cvt_x (blocks [0, 32768)) + 6 weight transposes (f32 -> bf16^T)
// in one dispatch. Transpose: 32x32 tiles, 256 flat threads.
// ---------------------------------------------------------------------------
__global__ __launch_bounds__(256) void prep_kernel(
    const float* __restrict__ x, const float* __restrict__ Wq,
    const float* __restrict__ Wk, const float* __restrict__ Wv,
    const float* __restrict__ Wo, const float* __restrict__ Wg,
    const float* __restrict__ Wout, bf16_t* __restrict__ concat,
    bf16_t* __restrict__ WqkvT, bf16_t* __restrict__ WoT,
    bf16_t* __restrict__ WgT, bf16_t* __restrict__ WoutT) {
  const int tid = threadIdx.x;
  int b = blockIdx.x;
  if (b < 32768) {  // cvt_x: x f32 -> bf16 into concat cols [2048,4096)
    const long i = ((long)b * 256 + tid) * 4;
    const long row = i >> 11;
    const int col = (int)(i & 2047);
    const float4 f = *(const float4*)&x[i];
    bf16x4 o;
    o[0] = (bf16_t)f.x; o[1] = (bf16_t)f.y; o[2] = (bf16_t)f.z; o[3] = (bf16_t)f.w;
    *(bf16x4*)&concat[row * 4096 + 2048 + col] = o;
    return;
  }
  b -= 32768;
  const float* in; bf16_t* out; int R, C;
  if (b < 4096)       { in = Wq;   out = WqkvT;                     R = 2048; C = 2048; }
  else if (b < 8192)  { in = Wk;   out = WqkvT + (size_t)2048*2048; R = 2048; C = 2048; b -= 4096; }
  else if (b < 12288) { in = Wv;   out = WqkvT + (size_t)4096*2048; R = 2048; C = 2048; b -= 8192; }
  else if (b < 16384) { in = Wo;   out = WoT;                       R = 2048; C = 2048; b -= 12288; }
  else if (b < 24576) { in = Wg;   out = WgT;                       R = 4096; C = 2048; b -= 16384; }
  else                { in = Wout; out = WoutT;                     R = 2048; C = 512;  b -= 24576; }
  const int CB = C / 32;
  const int c0 = (b % CB) * 32, r0 = (b / CB) * 32;
  __shared__ bf16_t tile[32][33];
  const int tx = tid & 31, ty = tid >> 5;
  for (int i = ty; i < 32; i += 8)
    tile[i][tx] = (bf16_t)in[(long)(r0 + i) * C + c0 + tx];
  __syncthreads();
  for (int i = ty; i < 32; i += 8)
    out[(long)(c0 + i) * R + r0 + tx] = tile[tx][i];
}

// ksum[c] = sum_b k[b][c]   (k = qkv cols [2048,4096), ld 6144)
__global__ __launch_bounds__(256) void ksum_kernel(const bf16_t* __restrict__ qkv,
                                                   float* __restrict__ ksum) {
  const int col = blockIdx.x * 256 + threadIdx.x;
  const int r0 = blockIdx.y * 256;
  const bf16_t* k = qkv + 2048;
  float s = 0.f;
  for (int r = 0; r < 256; ++r) s += (float)k[(long)(r0 + r) * 6144 + col];
  atomicAdd(&ksum[col], s);
}

// P[h][d][e] += sum_b k[b, h*128+d] * v[b, h*128+e]
__global__ __launch_bounds__(256) void kv_kernel(const bf16_t* __restrict__ qkv,
                                                 float* __restrict__ P) {
  const int h = blockIdx.x, sp = blockIdx.y;
  const int t = threadIdx.x;
  __shared__ __align__(16) bf16_t kS[64 * 128];
  __shared__ __align__(16) bf16_t vS[64 * 128];
  const int d0 = (t >> 4) * 8, e0 = (t & 15) * 8;
  const int srow = t >> 4, scol = (t & 15) * 8;
  float acc[8][8] = {};
  const bf16_t* kp = qkv + 2048 + h * 128;
  const bf16_t* vp = qkv + 4096 + h * 128;
  const long base = (long)sp * 512 * 6144;
  for (int c0 = 0; c0 < 512; c0 += 64) {
#pragma unroll
    for (int it = 0; it < 4; ++it) {
      load_lds16(kp + base + (long)(c0 + it * 16 + srow) * 6144 + scol, &kS[it * 2048 + t * 8]);
      load_lds16(vp + base + (long)(c0 + it * 16 + srow) * 6144 + scol, &vS[it * 2048 + t * 8]);
    }
    __syncthreads();
    for (int bb = 0; bb < 64; ++bb) {
      const bf16x8 kk = *(const bf16x8*)&kS[bb * 128 + d0];
      const bf16x8 vv = *(const bf16x8*)&vS[bb * 128 + e0];
      float kf[8], vf[8];
#pragma unroll
      for (int r = 0; r < 8; ++r) { kf[r] = (float)kk[r]; vf[r] = (float)vv[r]; }
#pragma unroll
      for (int a = 0; a < 8; ++a)
#pragma unroll
        for (int b2 = 0; b2 < 8; ++b2) acc[a][b2] += kf[a] * vf[b2];
    }
    __syncthreads();
  }
  float* Ph = P + (long)h * 16384;
#pragma unroll
  for (int a = 0; a < 8; ++a)
#pragma unroll
    for (int b2 = 0; b2 < 8; ++b2)
      atomicAdd(&Ph[(d0 + a) * 128 + e0 + b2], acc[a][b2]);
}

__global__ __launch_bounds__(256) void cvt_bf(const float* __restrict__ P,
                                              bf16_t* __restrict__ o, int n) {
  const int i = blockIdx.x * 256 + threadIdx.x;
  if (i < n) o[i] = (bf16_t)P[i];
}

// z[b][h] = 1 / (dot(q[b,h,:], ksum[h,:]) + 1e-6); then q *= z in-place
__global__ __launch_bounds__(256) void z_kernel(bf16_t* __restrict__ qkv,
                                                const float* __restrict__ ksum) {
  __shared__ float ks[2048];
  const int t = threadIdx.x;
  for (int i = t; i < 2048; i += 256) ks[i] = ksum[i];
  __syncthreads();
  const int b = blockIdx.x * 16 + (t >> 4);
  const int h = t & 15;
  bf16_t* qr = qkv + (long)b * 6144 + h * 128;
  bf16x8 qq[16];
  float s = 0.f;
#pragma unroll
  for (int i = 0; i < 16; ++i) {
    qq[i] = *(const bf16x8*)&qr[i * 8];
#pragma unroll
    for (int r = 0; r < 8; ++r) s += (float)qq[i][r] * ks[h * 128 + i * 8 + r];
  }
  const float z = 1.f / (s + 1e-6f);
#pragma unroll
  for (int i = 0; i < 16; ++i) {
#pragma unroll
    for (int r = 0; r < 8; ++r) qq[i][r] = (bf16_t)((float)qq[i][r] * z);
    *(bf16x8*)&qr[i * 8] = qq[i];
  }
}

extern "C" void kernel_launch(void* const* d_in, const int* in_sizes, int n_in,
                              void* d_out, int out_size, void* d_ws, size_t ws_size,
                              hipStream_t stream) {
  const float* x    = (const float*)d_in[0];
  const float* Wq   = (const float*)d_in[1];
  const float* Wk   = (const float*)d_in[2];
  const float* Wv   = (const float*)d_in[3];
  const float* Wo   = (const float*)d_in[4];
  const float* bo   = (const float*)d_in[5];
  const float* Wg   = (const float*)d_in[6];
  const float* bg   = (const float*)d_in[7];
  const float* Wout = (const float*)d_in[8];
  const float* bout = (const float*)d_in[9];

  char* ws = (char*)d_ws;
  size_t off = 0;
  auto alloc = [&](size_t bytes) -> void* {
    void* p = ws + off;
    off += (bytes + 255) & ~(size_t)255;
    return p;
  };
  bf16_t* concat = (bf16_t*)alloc((size_t)B_SZ * 4096 * 2);   // [op | x] bf16
  bf16_t* qkv    = (bf16_t*)alloc((size_t)B_SZ * 6144 * 2);   // [q | k | v]
  bf16_t* outb   = (bf16_t*)alloc((size_t)B_SZ * DIN * 2);
  bf16_t* WqkvT  = (bf16_t*)alloc((size_t)6144 * DIN * 2);
  bf16_t* WoT    = (bf16_t*)alloc((size_t)DIN * DV * 2);
  bf16_t* WgT    = (bf16_t*)alloc((size_t)DIN * 4096 * 2);
  bf16_t* WoutT  = (bf16_t*)alloc((size_t)DOUT * DIN * 2);
  float*  P      = (float*)alloc((size_t)NH * 128 * 128 * 4);
  bf16_t* kvbf   = (bf16_t*)alloc((size_t)NH * 128 * 128 * 2);
  bf16_t* G      = (bf16_t*)alloc((size_t)DIN * DK * 2);      // (blockdiag(kv) @ Wo)^T
  float*  ksum   = (float*)alloc((size_t)DK * 4);

  hipMemsetAsync(P, 0, (size_t)NH * 128 * 128 * 4, stream);
  hipMemsetAsync(ksum, 0, (size_t)DK * 4, stream);

  // single fused prep dispatch: cvt_x + all 6 weight transposes
  prep_kernel<<<32768 + 25600, 256, 0, stream>>>(x, Wq, Wk, Wv, Wo, Wg, Wout,
                                                 concat, WqkvT, WoT, WgT, WoutT);

  const bf16_t* xb = concat + 2048;  // bf16 x view, lda=4096

  // fused q|k|v projection: [B,2048] @ [2048,6144] -> qkv, relu-feat on q,k
  gemm_bt<1><<<dim3(48, 128, 1), 256, 0, stream>>>(xb, 4096, 0, WqkvT, 2048, 0,
                                                   qkv, 6144, 0, 2048, nullptr, nullptr);

  ksum_kernel<<<dim3(8, 64), 256, 0, stream>>>(qkv, ksum);
  kv_kernel<<<dim3(16, 32), 256, 0, stream>>>(qkv, P);
  cvt_bf<<<1024, 256, 0, stream>>>(P, kvbf, NH * 128 * 128);
  z_kernel<<<B_SZ / 16, 256, 0, stream>>>(qkv, ksum);  // also scales q by z

  // G[j][h*128+d] = sum_e kv_h[d][e] * WoT[j][h*128+e]  (per-head kv@Wo, transposed)
  gemm_bt<0><<<dim3(1, 16, 16), 256, 0, stream>>>(WoT, 2048, 128, kvbf, 128, 16384,
                                                  G, 2048, 128, 128, nullptr, nullptr);

  // out_proj = qz @ G^T + bo -> concat cols [0,2048)
  gemm_bt<2><<<dim3(16, 128, 1), 256, 0, stream>>>(qkv, 6144, 0, G, 2048, 0,
                                                   concat, 4096, 0, 2048, bo, nullptr);

  // gate GEMM over concat (K=4096), epilogue: sigmoid-mix -> outb
  gemm_bt<4><<<dim3(16, 128, 1), 256, 0, stream>>>(concat, 4096, 0, WgT, 4096, 0,
                                                   outb, 2048, 0, 4096, bg, x);

  // final: outb @ Wout + bout -> d_out (f32)
  gemm_bt<5><<<dim3(4, 128, 1), 256, 0, stream>>>(outb, 2048, 0, WoutT, 2048, 0,
                                                  d_out, 512, 0, 2048, bout, nullptr);
}